// Round 4
// baseline (1807.468 us; speedup 1.0000x reference)
//
#include <hip/hip_runtime.h>
#include <hip/hip_bf16.h>
#include <stdint.h>

// Problem constants (fixed by the reference)
#define N_NODES 100000
#define N_EDGES 1600000
#define F_NODE 128
#define F_EDGE 128
#define HIDDEN 256
#define OUT_F 128
#define K_DIM 256   // fan_in1 == HIDDEN == 256

// Partition scheme: nodes grouped into ranges of PN; per-partition bucket of
// bf16 edge rows appended in streaming order.
#define PN 96                 // nodes per partition (LDS acc = 96*128*4 = 48 KB)
#define NPART 1042            // ceil(100000 / 96)
#define CAP 2048              // slots per partition (mean 1536, sigma 39 -> 13 sigma)

using f32x4 = __attribute__((ext_vector_type(4))) float;
using s16x8 = __attribute__((ext_vector_type(8))) short;

typedef __attribute__((address_space(3))) unsigned lds_u32;
typedef __attribute__((address_space(1))) const unsigned gbl_u32;

static __device__ __forceinline__ short f2b(float f) {
  union { float f; unsigned u; } v; v.f = f;
  unsigned r = v.u + 0x7fffu + ((v.u >> 16) & 1u);
  return (short)(r >> 16);
}
static __device__ __forceinline__ float b2f(unsigned short h) {
  union { unsigned u; float f; } v; v.u = ((unsigned)h) << 16;
  return v.f;
}
static __device__ __forceinline__ void gld_lds16(const void* g, void* l) {
  __builtin_amdgcn_global_load_lds((gbl_u32*)g, (lds_u32*)l, 16, 0, 0);
}

// ---- Phase 1: stream edges, bf16-convert, append rows to partition buckets ----
// One wave per 64 consecutive edges: reads are fully coalesced+sequential;
// writes are 256B appends into ~1042 quasi-sequential partition streams.

__global__ __launch_bounds__(256) void k_scatter(const int* __restrict__ col,
                                                 const float* __restrict__ edge_attr,
                                                 unsigned* __restrict__ cursor,
                                                 unsigned short* __restrict__ ids,
                                                 short* __restrict__ buckets) {
  int w = (int)((blockIdx.x * (unsigned)blockDim.x + threadIdx.x) >> 6);
  int lane = threadIdx.x & 63;
  int e0 = w * 64;
  if (e0 >= N_EDGES) return;
  unsigned nid = (unsigned)col[e0 + lane];
  unsigned p = nid / PN;
  unsigned nl = nid - p * PN;
  unsigned slot = atomicAdd(&cursor[p], 1u);
  unsigned dst = 0xFFFFFFFFu;
  if (slot < CAP) {
    dst = p * CAP + slot;
    ids[dst] = (unsigned short)nl;
  }
  // cooperative bf16 row copies: iter j moves edge e0+j (512B read, 256B write)
  const float* src = edge_attr + (size_t)e0 * F_EDGE + lane * 2;
#pragma unroll 4
  for (int j = 0; j < 64; ++j) {
    unsigned d = __shfl(dst, j, 64);
    float2 v = *reinterpret_cast<const float2*>(src + (size_t)j * F_EDGE);
    short2 hv; hv.x = f2b(v.x); hv.y = f2b(v.y);
    if (d != 0xFFFFFFFFu)
      *reinterpret_cast<short2*>(buckets + (size_t)d * F_EDGE + lane * 2) = hv;
  }
}

// ---- Phase 2: per partition, sequential bucket read -> LDS f32 accumulate ----
// Block = 256 threads, partition = 96 nodes. Epilogue writes hin = [x | mean].

__global__ __launch_bounds__(256) void k_reduce(const unsigned* __restrict__ cursor,
                                                const unsigned short* __restrict__ ids,
                                                const short* __restrict__ buckets,
                                                const float* __restrict__ x,
                                                short* __restrict__ hin) {
  __shared__ float acc[PN * F_EDGE];   // 48 KB
  __shared__ unsigned cnts[PN];
  int p = blockIdx.x;
  int t = threadIdx.x;
  for (int i = t; i < PN * F_EDGE; i += 256) acc[i] = 0.f;
  for (int i = t; i < PN; i += 256) cnts[i] = 0u;
  __syncthreads();

  unsigned cnt = cursor[p]; if (cnt > CAP) cnt = CAP;
  int lane = t & 63, wv = t >> 6;
  unsigned base = (unsigned)p * CAP;
  for (unsigned s = wv; s < cnt; s += 4) {
    unsigned d = base + s;
    unsigned nl = ids[d];
    unsigned rv = *reinterpret_cast<const unsigned*>(buckets + (size_t)d * F_EDGE + lane * 2);
    float f0 = b2f((unsigned short)(rv & 0xffffu));
    float f1 = b2f((unsigned short)(rv >> 16));
    atomicAdd(&acc[nl * F_EDGE + lane * 2], f0);
    atomicAdd(&acc[nl * F_EDGE + lane * 2 + 1], f1);
    if (lane == 0) atomicAdd(&cnts[nl], 1u);
  }
  __syncthreads();

  int nodebase = p * PN;
  for (int n = wv; n < PN; n += 4) {
    int gn = nodebase + n;
    if (gn >= N_NODES) break;
    unsigned c = cnts[n];
    float inv = 1.0f / (float)(c > 0u ? c : 1u);
    float2 xv = *reinterpret_cast<const float2*>(x + (size_t)gn * F_NODE + 2 * lane);
    short2 hx; hx.x = f2b(xv.x); hx.y = f2b(xv.y);
    short* hrow = hin + (size_t)gn * K_DIM;
    *reinterpret_cast<short2*>(hrow + 2 * lane) = hx;
    short2 hm;
    hm.x = f2b(acc[n * F_EDGE + lane * 2] * inv);
    hm.y = f2b(acc[n * F_EDGE + lane * 2 + 1] * inv);
    *reinterpret_cast<short2*>(hrow + F_NODE + 2 * lane) = hm;
  }
}

// ---------------- weights f32 -> bf16 (both in one kernel) --------

__global__ void k_cvt2(const float* __restrict__ W1, const float* __restrict__ W2,
                       short* __restrict__ w1b, short* __restrict__ w2b) {
  int i = (blockIdx.x * blockDim.x + threadIdx.x) * 4;
  if (i < HIDDEN * K_DIM) {
    f32x4 v = *reinterpret_cast<const f32x4*>(W1 + i);
    short4 s; s.x = f2b(v[0]); s.y = f2b(v[1]); s.z = f2b(v[2]); s.w = f2b(v[3]);
    *reinterpret_cast<short4*>(w1b + i) = s;
  } else {
    int j = i - HIDDEN * K_DIM;
    if (j < OUT_F * HIDDEN) {
      f32x4 v = *reinterpret_cast<const f32x4*>(W2 + j);
      short4 s; s.x = f2b(v[0]); s.y = f2b(v[1]); s.z = f2b(v[2]); s.w = f2b(v[3]);
      *reinterpret_cast<short4*>(w2b + j) = s;
    }
  }
}

// ------------- fused MLP  out = relu(Hin@W1^T+b1)@W2^T + b2 -------
// Block: 128 rows, 512 threads (8 waves). Whole K=256 staged in LDS (64 KB),
// H1 kept in the SAME LDS buffer; never hits HBM. LDS byte-swizzle:
// kb' = kb ^ ((row&15)<<5) -> <=2-way bank aliasing on ds_read_b128 (free).

__global__ __launch_bounds__(512) void k_mlp(const short* __restrict__ A,
                                             const short* __restrict__ W1b,
                                             const float* __restrict__ b1,
                                             const short* __restrict__ W2b,
                                             const float* __restrict__ b2,
                                             float* __restrict__ out, int M) {
  __shared__ short lds[128 * 256];  // 64 KB
  const int t = threadIdx.x;
  const int lane = t & 63, wid = t >> 6;
  const int mrow0 = blockIdx.x * 128;
  const int lr = lane & 15;
  const int lkb = (lane >> 4) << 4;

  char* ldsb = (char*)lds;
#pragma unroll
  for (int j = 0; j < 8; ++j) {
    int chunk = j * 512 + t;
    int row = chunk >> 5;
    int kb = (chunk & 31) << 4;
    int src_kb = kb ^ ((row & 15) << 5);
    int grow = mrow0 + row; grow = grow < M ? grow : M - 1;
    const char* gsrc = (const char*)A + (size_t)grow * 512 + src_kb;
    char* ldst = ldsb + (size_t)(j * 512 + wid * 64) * 16;
    gld_lds16(gsrc, ldst);
  }
  __syncthreads();

  const int wr = wid >> 2;
  const int wc = wid & 3;
  f32x4 acc1[4][4] = {};
  for (int ksb = 0; ksb < 512; ksb += 64) {
    s16x8 af[4], bf[4];
#pragma unroll
    for (int m = 0; m < 4; ++m) {
      int row = wr * 64 + m * 16 + lr;
      int kb = (ksb + lkb) ^ ((row & 15) << 5);
      af[m] = *reinterpret_cast<const s16x8*>(ldsb + row * 512 + kb);
    }
#pragma unroll
    for (int nn = 0; nn < 4; ++nn) {
      int c = wc * 64 + nn * 16 + lr;
      bf[nn] = *reinterpret_cast<const s16x8*>(W1b + (size_t)c * 256 + ((ksb + lkb) >> 1));
    }
#pragma unroll
    for (int m = 0; m < 4; ++m)
#pragma unroll
      for (int nn = 0; nn < 4; ++nn)
        acc1[m][nn] = __builtin_amdgcn_mfma_f32_16x16x32_bf16(af[m], bf[nn], acc1[m][nn], 0, 0, 0);
  }
  __syncthreads();

#pragma unroll
  for (int nn = 0; nn < 4; ++nn) {
    int c = wc * 64 + nn * 16 + lr;
    float bv = b1[c];
#pragma unroll
    for (int m = 0; m < 4; ++m) {
#pragma unroll
      for (int j = 0; j < 4; ++j) {
        int r = wr * 64 + m * 16 + (lane >> 4) * 4 + j;
        float v = acc1[m][nn][j] + bv;
        v = v > 0.f ? v : 0.f;
        *reinterpret_cast<short*>(ldsb + r * 512 + ((c * 2) ^ ((r & 15) << 5))) = f2b(v);
      }
    }
  }
  __syncthreads();

  const int wr2 = wid >> 1;
  const int wc2 = wid & 1;
  f32x4 acc2[2][4] = {};
  for (int ksb = 0; ksb < 512; ksb += 64) {
    s16x8 af[2], bf[4];
#pragma unroll
    for (int m = 0; m < 2; ++m) {
      int row = wr2 * 32 + m * 16 + lr;
      int kb = (ksb + lkb) ^ ((row & 15) << 5);
      af[m] = *reinterpret_cast<const s16x8*>(ldsb + row * 512 + kb);
    }
#pragma unroll
    for (int nn = 0; nn < 4; ++nn) {
      int c = wc2 * 64 + nn * 16 + lr;
      bf[nn] = *reinterpret_cast<const s16x8*>(W2b + (size_t)c * 256 + ((ksb + lkb) >> 1));
    }
#pragma unroll
    for (int m = 0; m < 2; ++m)
#pragma unroll
      for (int nn = 0; nn < 4; ++nn)
        acc2[m][nn] = __builtin_amdgcn_mfma_f32_16x16x32_bf16(af[m], bf[nn], acc2[m][nn], 0, 0, 0);
  }
#pragma unroll
  for (int nn = 0; nn < 4; ++nn) {
    int c = wc2 * 64 + nn * 16 + lr;
    float bv = b2[c];
#pragma unroll
    for (int m = 0; m < 2; ++m) {
#pragma unroll
      for (int j = 0; j < 4; ++j) {
        int r = mrow0 + wr2 * 32 + m * 16 + (lane >> 4) * 4 + j;
        if (r < M) out[(size_t)r * OUT_F + c] = acc2[m][nn][j] + bv;
      }
    }
  }
}

// ---------------- launch ----------------

extern "C" void kernel_launch(void* const* d_in, const int* in_sizes, int n_in,
                              void* d_out, int out_size, void* d_ws, size_t ws_size,
                              hipStream_t stream) {
  const float* x         = (const float*)d_in[0];
  const int*   edge_idx  = (const int*)d_in[1];      // [2 x N_EDGES], int32
  const int*   col       = edge_idx + N_EDGES;       // row 1 = destinations
  const float* edge_attr = (const float*)d_in[2];
  const float* W1        = (const float*)d_in[3];
  const float* b1        = (const float*)d_in[4];
  const float* W2        = (const float*)d_in[5];
  const float* b2        = (const float*)d_in[6];
  float* out = (float*)d_out;

  // workspace layout (bytes), all 16B-aligned
  char* ws = (char*)d_ws;
  unsigned*       cursor  = (unsigned*)      (ws + 0);         // 1042*4 = 4168
  unsigned short* ids     = (unsigned short*)(ws + 4224);      // 1042*2048*2 = 4,268,032
  short*          buckets = (short*)         (ws + 4272256);   // 1042*2048*128*2 = 546,308,096
  short*          hin     = (short*)         (ws + 550580352); // 51,200,000
  short*          w1b     = (short*)         (ws + 601780352); // 131,072
  short*          w2b     = (short*)         (ws + 601911424); // 65,536
  // total ~602 MB

  hipMemsetAsync(cursor, 0, NPART * 4, stream);

  k_cvt2   <<<(HIDDEN * K_DIM + OUT_F * HIDDEN) / 4 / 256, 256, 0, stream>>>(W1, W2, w1b, w2b);
  k_scatter<<<N_EDGES / 64 / 4, 256, 0, stream>>>(col, edge_attr, cursor, ids, buckets);
  k_reduce <<<NPART, 256, 0, stream>>>(cursor, ids, buckets, x, hin);
  k_mlp    <<<(N_NODES + 127) / 128, 512, 0, stream>>>(hin, w1b, b1, w2b, b2, out, N_NODES);
}

// Round 5
// 549.643 us; speedup vs baseline: 3.2884x; 3.2884x over previous
//
#include <hip/hip_runtime.h>
#include <hip/hip_bf16.h>
#include <stdint.h>

// Problem constants (fixed by the reference)
#define N_NODES 100000
#define N_EDGES 1600000
#define F_NODE 128
#define F_EDGE 128
#define HIDDEN 256
#define OUT_F 128
#define K_DIM 256   // fan_in1 == HIDDEN == 256
#define CAP 64      // bucket slots/node; P(Poisson(16) > 64) ~ e^-125

using f32x4 = __attribute__((ext_vector_type(4))) float;
using s16x8 = __attribute__((ext_vector_type(8))) short;

static __device__ __forceinline__ short f2b(float f) {
  // f32 -> bf16 round-to-nearest-even (finite inputs)
  union { float f; unsigned u; } v; v.f = f;
  unsigned r = v.u + 0x7fffu + ((v.u >> 16) & 1u);
  return (short)(r >> 16);
}

// ---- Phase 1: bucket edge ids by destination node (fixed-capacity) ----

__global__ void k_fill(const int* __restrict__ col,
                       unsigned* __restrict__ cursor,
                       unsigned* __restrict__ ids) {
  int e = blockIdx.x * blockDim.x + threadIdx.x;
  if (e < N_EDGES) {
    int n = col[e];
    unsigned slot = atomicAdd(&cursor[n], 1u);
    if (slot < CAP) ids[(size_t)n * CAP + slot] = (unsigned)e;
  }
}

// ---- Phase 2: weights f32 -> bf16 ----

__global__ void k_cvt2(const float* __restrict__ W1, const float* __restrict__ W2,
                       short* __restrict__ w1b, short* __restrict__ w2b) {
  int i = (blockIdx.x * blockDim.x + threadIdx.x) * 4;
  if (i < HIDDEN * K_DIM) {
    f32x4 v = *reinterpret_cast<const f32x4*>(W1 + i);
    short4 s; s.x = f2b(v[0]); s.y = f2b(v[1]); s.z = f2b(v[2]); s.w = f2b(v[3]);
    *reinterpret_cast<short4*>(w1b + i) = s;
  } else {
    int j = i - HIDDEN * K_DIM;
    if (j < OUT_F * HIDDEN) {
      f32x4 v = *reinterpret_cast<const f32x4*>(W2 + j);
      short4 s; s.x = f2b(v[0]); s.y = f2b(v[1]); s.z = f2b(v[2]); s.w = f2b(v[3]);
      *reinterpret_cast<short4*>(w2b + j) = s;
    }
  }
}

// ---- Phase 3: FUSED gather + MLP.  Block = 512 thr (8 waves) = 128 nodes. ----
// Wave w gathers nodes w*16..w*16+15: random 512B edge-row reads (8 in flight),
// f32 register accumulate, mean, bf16 -> swizzled LDS A-tile [x | agg].
// Then: GEMM1 (A@W1^T+b1, relu) -> H1 bf16 back into SAME LDS; GEMM2 -> out.
// LDS byte-swizzle kb' = kb ^ ((row&15)<<5): ds_read_b128 fragments <=2-way.

__global__ __launch_bounds__(512) void k_fused(const float* __restrict__ x,
                                               const float* __restrict__ edge_attr,
                                               const unsigned* __restrict__ cursor,
                                               const unsigned* __restrict__ ids,
                                               const short* __restrict__ W1b,
                                               const float* __restrict__ b1,
                                               const short* __restrict__ W2b,
                                               const float* __restrict__ b2,
                                               float* __restrict__ out, int M) {
  __shared__ short lds[128 * 256];  // 64 KB
  const int t = threadIdx.x;
  const int lane = t & 63, wid = t >> 6;
  const int half = lane >> 5, l32 = lane & 31;
  const int mrow0 = blockIdx.x * 128;
  char* ldsb = (char*)lds;

  // ---- Phase A: gather + build A-tile in LDS ----
  const float* eb = edge_attr + 4 * l32;
  for (int k = 0; k < 16; ++k) {
    int r = wid * 16 + k;            // local row 0..127
    int gn = mrow0 + r;              // global node
    int gnc = gn < M ? gn : M - 1;   // clamped for x read
    unsigned cnt = 0;
    if (gn < M) { cnt = cursor[gn]; cnt = cnt > CAP ? CAP : cnt; }
    const unsigned* idp = ids + (size_t)gnc * CAP;
    f32x4 a = {0.f, 0.f, 0.f, 0.f};
    unsigned i = 0;
    for (; i + 8 <= cnt; i += 8) {   // 8 rows in flight (4 per half-wave)
      unsigned e0 = idp[i + 0 + half];
      unsigned e1 = idp[i + 2 + half];
      unsigned e2 = idp[i + 4 + half];
      unsigned e3 = idp[i + 6 + half];
      f32x4 v0 = *reinterpret_cast<const f32x4*>(eb + (size_t)e0 * F_EDGE);
      f32x4 v1 = *reinterpret_cast<const f32x4*>(eb + (size_t)e1 * F_EDGE);
      f32x4 v2 = *reinterpret_cast<const f32x4*>(eb + (size_t)e2 * F_EDGE);
      f32x4 v3 = *reinterpret_cast<const f32x4*>(eb + (size_t)e3 * F_EDGE);
      a += v0 + v1 + v2 + v3;
    }
    for (; i + 2 <= cnt; i += 2) {
      unsigned e = idp[i + half];
      a += *reinterpret_cast<const f32x4*>(eb + (size_t)e * F_EDGE);
    }
    if (i < cnt && half == 0) {
      unsigned e = idp[i];
      a += *reinterpret_cast<const f32x4*>(eb + (size_t)e * F_EDGE);
    }
    // combine halves (both halves end with full sum)
    f32x4 bsw;
    bsw[0] = __shfl_xor(a[0], 32); bsw[1] = __shfl_xor(a[1], 32);
    bsw[2] = __shfl_xor(a[2], 32); bsw[3] = __shfl_xor(a[3], 32);
    a += bsw;
    float inv = 1.0f / (float)(cnt > 0u ? cnt : 1u);
    // x part: 64 lanes x float2 -> short2 at bytes [0,256)
    float2 xv = *reinterpret_cast<const float2*>(x + (size_t)gnc * F_NODE + 2 * lane);
    short2 hx; hx.x = f2b(xv.x); hx.y = f2b(xv.y);
    *reinterpret_cast<short2*>(ldsb + r * 512 + ((4 * lane) ^ ((r & 15) << 5))) = hx;
    // agg part: lanes 0..31 write short4 at bytes [256,512)
    if (half == 0) {
      short4 hm;
      hm.x = f2b(a[0] * inv); hm.y = f2b(a[1] * inv);
      hm.z = f2b(a[2] * inv); hm.w = f2b(a[3] * inv);
      *reinterpret_cast<short4*>(ldsb + r * 512 + ((256 + 8 * l32) ^ ((r & 15) << 5))) = hm;
    }
  }
  __syncthreads();

  // ---- GEMM1: H1[128x256] = relu(A @ W1^T + b1) ----
  const int lr = lane & 15;
  const int lkb = (lane >> 4) << 4;  // k byte offset within fragment
  const int wr = wid >> 2;           // 0..1: 64-row half
  const int wc = wid & 3;            // 0..3: 64-col quarter
  f32x4 acc1[4][4] = {};
  for (int ksb = 0; ksb < 512; ksb += 64) {
    s16x8 af[4], bf[4];
#pragma unroll
    for (int m = 0; m < 4; ++m) {
      int row = wr * 64 + m * 16 + lr;
      int kb = (ksb + lkb) ^ ((row & 15) << 5);
      af[m] = *reinterpret_cast<const s16x8*>(ldsb + row * 512 + kb);
    }
#pragma unroll
    for (int nn = 0; nn < 4; ++nn) {
      int c = wc * 64 + nn * 16 + lr;
      bf[nn] = *reinterpret_cast<const s16x8*>(W1b + (size_t)c * 256 + ((ksb + lkb) >> 1));
    }
#pragma unroll
    for (int m = 0; m < 4; ++m)
#pragma unroll
      for (int nn = 0; nn < 4; ++nn)
        acc1[m][nn] = __builtin_amdgcn_mfma_f32_16x16x32_bf16(af[m], bf[nn], acc1[m][nn], 0, 0, 0);
  }
  __syncthreads();  // everyone done reading A before overwriting with H1

  // epilogue 1: bias+relu -> bf16 into LDS (same swizzle)
#pragma unroll
  for (int nn = 0; nn < 4; ++nn) {
    int c = wc * 64 + nn * 16 + lr;
    float bv = b1[c];
#pragma unroll
    for (int m = 0; m < 4; ++m) {
#pragma unroll
      for (int j = 0; j < 4; ++j) {
        int r = wr * 64 + m * 16 + (lane >> 4) * 4 + j;
        float v = acc1[m][nn][j] + bv;
        v = v > 0.f ? v : 0.f;
        *reinterpret_cast<short*>(ldsb + r * 512 + ((c * 2) ^ ((r & 15) << 5))) = f2b(v);
      }
    }
  }
  __syncthreads();

  // ---- GEMM2: out[128x128] = H1 @ W2^T + b2 ----
  const int wr2 = wid >> 1;  // 0..3: 32-row strip
  const int wc2 = wid & 1;   // 0..1: 64-col half
  f32x4 acc2[2][4] = {};
  for (int ksb = 0; ksb < 512; ksb += 64) {
    s16x8 af[2], bf[4];
#pragma unroll
    for (int m = 0; m < 2; ++m) {
      int row = wr2 * 32 + m * 16 + lr;
      int kb = (ksb + lkb) ^ ((row & 15) << 5);
      af[m] = *reinterpret_cast<const s16x8*>(ldsb + row * 512 + kb);
    }
#pragma unroll
    for (int nn = 0; nn < 4; ++nn) {
      int c = wc2 * 64 + nn * 16 + lr;
      bf[nn] = *reinterpret_cast<const s16x8*>(W2b + (size_t)c * 256 + ((ksb + lkb) >> 1));
    }
#pragma unroll
    for (int m = 0; m < 2; ++m)
#pragma unroll
      for (int nn = 0; nn < 4; ++nn)
        acc2[m][nn] = __builtin_amdgcn_mfma_f32_16x16x32_bf16(af[m], bf[nn], acc2[m][nn], 0, 0, 0);
  }
#pragma unroll
  for (int nn = 0; nn < 4; ++nn) {
    int c = wc2 * 64 + nn * 16 + lr;
    float bv = b2[c];
#pragma unroll
    for (int m = 0; m < 2; ++m) {
#pragma unroll
      for (int j = 0; j < 4; ++j) {
        int r = mrow0 + wr2 * 32 + m * 16 + (lane >> 4) * 4 + j;
        if (r < M) out[(size_t)r * OUT_F + c] = acc2[m][nn][j] + bv;
      }
    }
  }
}

// ---------------- launch ----------------

extern "C" void kernel_launch(void* const* d_in, const int* in_sizes, int n_in,
                              void* d_out, int out_size, void* d_ws, size_t ws_size,
                              hipStream_t stream) {
  const float* x         = (const float*)d_in[0];
  const int*   edge_idx  = (const int*)d_in[1];      // [2 x N_EDGES], int32
  const int*   col       = edge_idx + N_EDGES;       // row 1 = destinations
  const float* edge_attr = (const float*)d_in[2];
  const float* W1        = (const float*)d_in[3];
  const float* b1        = (const float*)d_in[4];
  const float* W2        = (const float*)d_in[5];
  const float* b2        = (const float*)d_in[6];
  float* out = (float*)d_out;

  // workspace layout (bytes), 16B-aligned
  char* ws = (char*)d_ws;
  unsigned* cursor = (unsigned*)(ws + 0);          // 400,000
  unsigned* ids    = (unsigned*)(ws + 400000);     // 100000*64*4 = 25,600,000
  short*    w1b    = (short*)   (ws + 26000000);   // 131,072
  short*    w2b    = (short*)   (ws + 26131072);   // 65,536
  // total ~26.2 MB

  hipMemsetAsync(cursor, 0, 400000, stream);

  k_cvt2 <<<(HIDDEN * K_DIM + OUT_F * HIDDEN) / 4 / 256, 256, 0, stream>>>(W1, W2, w1b, w2b);
  k_fill <<<(N_EDGES + 255) / 256, 256, 0, stream>>>(col, cursor, ids);
  k_fused<<<(N_NODES + 127) / 128, 512, 0, stream>>>(x, edge_attr, cursor, ids,
                                                     w1b, b1, w2b, b2, out, N_NODES);
}

// Round 6
// 433.172 us; speedup vs baseline: 4.1726x; 1.2689x over previous
//
#include <hip/hip_runtime.h>
#include <hip/hip_bf16.h>
#include <stdint.h>

// Problem constants (fixed by the reference)
#define N_NODES 100000
#define N_EDGES 1600000
#define F_NODE 128
#define F_EDGE 128
#define HIDDEN 256
#define OUT_F 128
#define K_DIM 256   // fan_in1 == HIDDEN == 256
#define CAP 64      // bucket slots/node; P(count > 64 | mean 16) ~ e^-125

using f32x4 = __attribute__((ext_vector_type(4))) float;
using s16x8 = __attribute__((ext_vector_type(8))) short;

typedef __attribute__((address_space(3))) unsigned lds_u32;
typedef __attribute__((address_space(1))) const unsigned gbl_u32;

static __device__ __forceinline__ short f2b(float f) {
  // f32 -> bf16 round-to-nearest-even (finite inputs)
  union { float f; unsigned u; } v; v.f = f;
  unsigned r = v.u + 0x7fffu + ((v.u >> 16) & 1u);
  return (short)(r >> 16);
}
static __device__ __forceinline__ void gld_lds16(const void* g, void* l) {
  __builtin_amdgcn_global_load_lds((gbl_u32*)g, (lds_u32*)l, 16, 0, 0);
}

// ---- Phase 1: bucket edge ids by destination node (fixed-capacity) ----

__global__ void k_fill(const int* __restrict__ col,
                       unsigned* __restrict__ cursor,
                       unsigned* __restrict__ ids) {
  int e = blockIdx.x * blockDim.x + threadIdx.x;
  if (e < N_EDGES) {
    int n = col[e];
    unsigned slot = atomicAdd(&cursor[n], 1u);
    if (slot < CAP) ids[(size_t)n * CAP + slot] = (unsigned)e;
  }
}

// ---- Phase 2: weights f32 -> bf16 ----

__global__ void k_cvt2(const float* __restrict__ W1, const float* __restrict__ W2,
                       short* __restrict__ w1b, short* __restrict__ w2b) {
  int i = (blockIdx.x * blockDim.x + threadIdx.x) * 4;
  if (i < HIDDEN * K_DIM) {
    f32x4 v = *reinterpret_cast<const f32x4*>(W1 + i);
    short4 s; s.x = f2b(v[0]); s.y = f2b(v[1]); s.z = f2b(v[2]); s.w = f2b(v[3]);
    *reinterpret_cast<short4*>(w1b + i) = s;
  } else {
    int j = i - HIDDEN * K_DIM;
    if (j < OUT_F * HIDDEN) {
      f32x4 v = *reinterpret_cast<const f32x4*>(W2 + j);
      short4 s; s.x = f2b(v[0]); s.y = f2b(v[1]); s.z = f2b(v[2]); s.w = f2b(v[3]);
      *reinterpret_cast<short4*>(w2b + j) = s;
    }
  }
}

// ---- Phase 3: gather-mean at MAX occupancy (no LDS, one wave per node) ----
// Half-wave (32 lanes x float4) reads one 512B edge row per load; 8 rows in
// flight per wave. Writes hin = [x | agg] bf16 rows linearly.

__global__ void k_agg(const float* __restrict__ x,
                      const float* __restrict__ edge_attr,
                      const unsigned* __restrict__ cursor,
                      const unsigned* __restrict__ ids,
                      short* __restrict__ hin) {
  int n = (int)((blockIdx.x * (unsigned)blockDim.x + threadIdx.x) >> 6);
  int lane = threadIdx.x & 63;
  if (n >= N_NODES) return;
  int half = lane >> 5, l32 = lane & 31;
  unsigned cnt = cursor[n]; cnt = cnt > CAP ? CAP : cnt;
  const unsigned* idp = ids + (size_t)n * CAP;
  f32x4 a = {0.f, 0.f, 0.f, 0.f};
  const float* eb = edge_attr + 4 * l32;
  unsigned i = 0;
  for (; i + 8 <= cnt; i += 8) {
    unsigned e0 = idp[i + 0 + half];
    unsigned e1 = idp[i + 2 + half];
    unsigned e2 = idp[i + 4 + half];
    unsigned e3 = idp[i + 6 + half];
    f32x4 v0 = *reinterpret_cast<const f32x4*>(eb + (size_t)e0 * F_EDGE);
    f32x4 v1 = *reinterpret_cast<const f32x4*>(eb + (size_t)e1 * F_EDGE);
    f32x4 v2 = *reinterpret_cast<const f32x4*>(eb + (size_t)e2 * F_EDGE);
    f32x4 v3 = *reinterpret_cast<const f32x4*>(eb + (size_t)e3 * F_EDGE);
    a += v0 + v1 + v2 + v3;
  }
  for (; i + 2 <= cnt; i += 2) {
    unsigned e = idp[i + half];
    a += *reinterpret_cast<const f32x4*>(eb + (size_t)e * F_EDGE);
  }
  if (i < cnt && half == 0) {
    unsigned e = idp[i];
    a += *reinterpret_cast<const f32x4*>(eb + (size_t)e * F_EDGE);
  }
  // combine halves (both end with the full sum)
  f32x4 bsw;
  bsw[0] = __shfl_xor(a[0], 32); bsw[1] = __shfl_xor(a[1], 32);
  bsw[2] = __shfl_xor(a[2], 32); bsw[3] = __shfl_xor(a[3], 32);
  a += bsw;
  float inv = 1.0f / (float)(cnt > 0u ? cnt : 1u);
  // x part: 64 lanes x float2
  float2 xv = *reinterpret_cast<const float2*>(x + (size_t)n * F_NODE + 2 * lane);
  short2 hx; hx.x = f2b(xv.x); hx.y = f2b(xv.y);
  short* hrow = hin + (size_t)n * K_DIM;
  *reinterpret_cast<short2*>(hrow + 2 * lane) = hx;
  // agg part: lanes 0..31 write short4
  if (half == 0) {
    short4 hm;
    hm.x = f2b(a[0] * inv); hm.y = f2b(a[1] * inv);
    hm.z = f2b(a[2] * inv); hm.w = f2b(a[3] * inv);
    *reinterpret_cast<short4*>(hrow + F_NODE + 4 * l32) = hm;
  }
}

// ------------- Phase 4: fused MLP  out = relu(Hin@W1^T+b1)@W2^T + b2 -------
// Block: 128 rows, 512 threads (8 waves). Whole K=256 staged in LDS (64 KB)
// via global_load_lds (pre-swizzled source); H1 kept in the SAME LDS buffer.
// LDS byte-swizzle kb' = kb ^ ((row&15)<<5): ds_read_b128 fragments <=2-way.

__global__ __launch_bounds__(512) void k_mlp(const short* __restrict__ A,
                                             const short* __restrict__ W1b,
                                             const float* __restrict__ b1,
                                             const short* __restrict__ W2b,
                                             const float* __restrict__ b2,
                                             float* __restrict__ out, int M) {
  __shared__ short lds[128 * 256];  // 64 KB
  const int t = threadIdx.x;
  const int lane = t & 63, wid = t >> 6;
  const int mrow0 = blockIdx.x * 128;
  const int lr = lane & 15;
  const int lkb = (lane >> 4) << 4;

  char* ldsb = (char*)lds;
#pragma unroll
  for (int j = 0; j < 8; ++j) {
    int chunk = j * 512 + t;
    int row = chunk >> 5;
    int kb = (chunk & 31) << 4;
    int src_kb = kb ^ ((row & 15) << 5);
    int grow = mrow0 + row; grow = grow < M ? grow : M - 1;
    const char* gsrc = (const char*)A + (size_t)grow * 512 + src_kb;
    char* ldst = ldsb + (size_t)(j * 512 + wid * 64) * 16;
    gld_lds16(gsrc, ldst);
  }
  __syncthreads();

  const int wr = wid >> 2;
  const int wc = wid & 3;
  f32x4 acc1[4][4] = {};
  for (int ksb = 0; ksb < 512; ksb += 64) {
    s16x8 af[4], bf[4];
#pragma unroll
    for (int m = 0; m < 4; ++m) {
      int row = wr * 64 + m * 16 + lr;
      int kb = (ksb + lkb) ^ ((row & 15) << 5);
      af[m] = *reinterpret_cast<const s16x8*>(ldsb + row * 512 + kb);
    }
#pragma unroll
    for (int nn = 0; nn < 4; ++nn) {
      int c = wc * 64 + nn * 16 + lr;
      bf[nn] = *reinterpret_cast<const s16x8*>(W1b + (size_t)c * 256 + ((ksb + lkb) >> 1));
    }
#pragma unroll
    for (int m = 0; m < 4; ++m)
#pragma unroll
      for (int nn = 0; nn < 4; ++nn)
        acc1[m][nn] = __builtin_amdgcn_mfma_f32_16x16x32_bf16(af[m], bf[nn], acc1[m][nn], 0, 0, 0);
  }
  __syncthreads();

#pragma unroll
  for (int nn = 0; nn < 4; ++nn) {
    int c = wc * 64 + nn * 16 + lr;
    float bv = b1[c];
#pragma unroll
    for (int m = 0; m < 4; ++m) {
#pragma unroll
      for (int j = 0; j < 4; ++j) {
        int r = wr * 64 + m * 16 + (lane >> 4) * 4 + j;
        float v = acc1[m][nn][j] + bv;
        v = v > 0.f ? v : 0.f;
        *reinterpret_cast<short*>(ldsb + r * 512 + ((c * 2) ^ ((r & 15) << 5))) = f2b(v);
      }
    }
  }
  __syncthreads();

  const int wr2 = wid >> 1;
  const int wc2 = wid & 1;
  f32x4 acc2[2][4] = {};
  for (int ksb = 0; ksb < 512; ksb += 64) {
    s16x8 af[2], bf[4];
#pragma unroll
    for (int m = 0; m < 2; ++m) {
      int row = wr2 * 32 + m * 16 + lr;
      int kb = (ksb + lkb) ^ ((row & 15) << 5);
      af[m] = *reinterpret_cast<const s16x8*>(ldsb + row * 512 + kb);
    }
#pragma unroll
    for (int nn = 0; nn < 4; ++nn) {
      int c = wc2 * 64 + nn * 16 + lr;
      bf[nn] = *reinterpret_cast<const s16x8*>(W2b + (size_t)c * 256 + ((ksb + lkb) >> 1));
    }
#pragma unroll
    for (int m = 0; m < 2; ++m)
#pragma unroll
      for (int nn = 0; nn < 4; ++nn)
        acc2[m][nn] = __builtin_amdgcn_mfma_f32_16x16x32_bf16(af[m], bf[nn], acc2[m][nn], 0, 0, 0);
  }
#pragma unroll
  for (int nn = 0; nn < 4; ++nn) {
    int c = wc2 * 64 + nn * 16 + lr;
    float bv = b2[c];
#pragma unroll
    for (int m = 0; m < 2; ++m) {
#pragma unroll
      for (int j = 0; j < 4; ++j) {
        int r = mrow0 + wr2 * 32 + m * 16 + (lane >> 4) * 4 + j;
        if (r < M) out[(size_t)r * OUT_F + c] = acc2[m][nn][j] + bv;
      }
    }
  }
}

// ---------------- launch ----------------

extern "C" void kernel_launch(void* const* d_in, const int* in_sizes, int n_in,
                              void* d_out, int out_size, void* d_ws, size_t ws_size,
                              hipStream_t stream) {
  const float* x         = (const float*)d_in[0];
  const int*   edge_idx  = (const int*)d_in[1];      // [2 x N_EDGES], int32
  const int*   col       = edge_idx + N_EDGES;       // row 1 = destinations
  const float* edge_attr = (const float*)d_in[2];
  const float* W1        = (const float*)d_in[3];
  const float* b1        = (const float*)d_in[4];
  const float* W2        = (const float*)d_in[5];
  const float* b2        = (const float*)d_in[6];
  float* out = (float*)d_out;

  // workspace layout (bytes), 16B-aligned
  char* ws = (char*)d_ws;
  unsigned* cursor = (unsigned*)(ws + 0);          // 400,000
  unsigned* ids    = (unsigned*)(ws + 400000);     // 100000*64*4 = 25,600,000
  short*    hin    = (short*)   (ws + 26000000);   // 51,200,000
  short*    w1b    = (short*)   (ws + 77200000);   // 131,072
  short*    w2b    = (short*)   (ws + 77331072);   // 65,536
  // total ~77.4 MB

  hipMemsetAsync(cursor, 0, 400000, stream);

  k_cvt2<<<(HIDDEN * K_DIM + OUT_F * HIDDEN) / 4 / 256, 256, 0, stream>>>(W1, W2, w1b, w2b);
  k_fill<<<(N_EDGES + 255) / 256, 256, 0, stream>>>(col, cursor, ids);
  k_agg <<<(N_NODES * 64 + 255) / 256, 256, 0, stream>>>(x, edge_attr, cursor, ids, hin);
  k_mlp <<<(N_NODES + 127) / 128, 512, 0, stream>>>(hin, w1b, b1, w2b, b2, out, N_NODES);
}

// Round 7
// 411.822 us; speedup vs baseline: 4.3890x; 1.0518x over previous
//
#include <hip/hip_runtime.h>
#include <hip/hip_bf16.h>
#include <stdint.h>

// Problem constants (fixed by the reference)
#define N_NODES 100000
#define N_EDGES 1600000
#define F_NODE 128
#define F_EDGE 128
#define HIDDEN 256
#define OUT_F 128
#define K_DIM 256   // fan_in1 == HIDDEN == 256
#define CAP 64      // bucket slots/node; P(count > 64 | mean 16) ~ e^-125

#define FILL_BLOCKS ((N_EDGES + 255) / 256)                  // 6250
#define CVT_BLOCKS  ((HIDDEN * K_DIM + OUT_F * HIDDEN) / 4 / 256)  // 96

using f32x4 = __attribute__((ext_vector_type(4))) float;
using s16x8 = __attribute__((ext_vector_type(8))) short;

typedef __attribute__((address_space(3))) unsigned lds_u32;
typedef __attribute__((address_space(1))) const unsigned gbl_u32;

static __device__ __forceinline__ short f2b(float f) {
  // f32 -> bf16 round-to-nearest-even (finite inputs)
  union { float f; unsigned u; } v; v.f = f;
  unsigned r = v.u + 0x7fffu + ((v.u >> 16) & 1u);
  return (short)(r >> 16);
}
static __device__ __forceinline__ void gld_lds16(const void* g, void* l) {
  __builtin_amdgcn_global_load_lds((gbl_u32*)g, (lds_u32*)l, 16, 0, 0);
}

// ---- Phase 1: bucket edge ids by node (fixed-capacity) + weight cvt fused ----

__global__ void k_fill_cvt(const int* __restrict__ col,
                           unsigned* __restrict__ cursor,
                           unsigned* __restrict__ ids,
                           const float* __restrict__ W1,
                           const float* __restrict__ W2,
                           short* __restrict__ w1b,
                           short* __restrict__ w2b) {
  int bid = blockIdx.x;
  if (bid < FILL_BLOCKS) {
    int e = bid * 256 + threadIdx.x;
    if (e < N_EDGES) {
      int n = col[e];
      unsigned slot = atomicAdd(&cursor[n], 1u);
      if (slot < CAP) ids[(size_t)n * CAP + slot] = (unsigned)e;
    }
  } else {
    int i = ((bid - FILL_BLOCKS) * 256 + threadIdx.x) * 4;
    if (i < HIDDEN * K_DIM) {
      f32x4 v = *reinterpret_cast<const f32x4*>(W1 + i);
      short4 s; s.x = f2b(v[0]); s.y = f2b(v[1]); s.z = f2b(v[2]); s.w = f2b(v[3]);
      *reinterpret_cast<short4*>(w1b + i) = s;
    } else {
      int j = i - HIDDEN * K_DIM;
      if (j < OUT_F * HIDDEN) {
        f32x4 v = *reinterpret_cast<const f32x4*>(W2 + j);
        short4 s; s.x = f2b(v[0]); s.y = f2b(v[1]); s.z = f2b(v[2]); s.w = f2b(v[3]);
        *reinterpret_cast<short4*>(w2b + j) = s;
      }
    }
  }
}

// ---- Phase 2: gather-mean at MAX occupancy (no LDS, one wave per node) ----
// Half-wave (32 lanes x float4) reads one 512B edge row per load; 8 rows in
// flight per wave; __launch_bounds__(256,8) pins VGPR <= 64 so 8 waves/SIMD.

__global__ __launch_bounds__(256, 8) void k_agg(const float* __restrict__ x,
                                                const float* __restrict__ edge_attr,
                                                const unsigned* __restrict__ cursor,
                                                const unsigned* __restrict__ ids,
                                                short* __restrict__ hin) {
  int n = (int)((blockIdx.x * (unsigned)blockDim.x + threadIdx.x) >> 6);
  int lane = threadIdx.x & 63;
  if (n >= N_NODES) return;
  int half = lane >> 5, l32 = lane & 31;
  unsigned cnt = cursor[n]; cnt = cnt > CAP ? CAP : cnt;
  const unsigned* idp = ids + (size_t)n * CAP;
  f32x4 a = {0.f, 0.f, 0.f, 0.f};
  const float* eb = edge_attr + 4 * l32;
  unsigned i = 0;
  for (; i + 8 <= cnt; i += 8) {
    unsigned e0 = idp[i + 0 + half];
    unsigned e1 = idp[i + 2 + half];
    unsigned e2 = idp[i + 4 + half];
    unsigned e3 = idp[i + 6 + half];
    f32x4 v0 = *reinterpret_cast<const f32x4*>(eb + (size_t)e0 * F_EDGE);
    f32x4 v1 = *reinterpret_cast<const f32x4*>(eb + (size_t)e1 * F_EDGE);
    f32x4 v2 = *reinterpret_cast<const f32x4*>(eb + (size_t)e2 * F_EDGE);
    f32x4 v3 = *reinterpret_cast<const f32x4*>(eb + (size_t)e3 * F_EDGE);
    a += (v0 + v1) + (v2 + v3);
  }
  for (; i + 2 <= cnt; i += 2) {
    unsigned e = idp[i + half];
    a += *reinterpret_cast<const f32x4*>(eb + (size_t)e * F_EDGE);
  }
  if (i < cnt && half == 0) {
    unsigned e = idp[i];
    a += *reinterpret_cast<const f32x4*>(eb + (size_t)e * F_EDGE);
  }
  // combine halves (both end with the full sum)
  f32x4 bsw;
  bsw[0] = __shfl_xor(a[0], 32); bsw[1] = __shfl_xor(a[1], 32);
  bsw[2] = __shfl_xor(a[2], 32); bsw[3] = __shfl_xor(a[3], 32);
  a += bsw;
  float inv = 1.0f / (float)(cnt > 0u ? cnt : 1u);
  // x part: 64 lanes x float2
  float2 xv = *reinterpret_cast<const float2*>(x + (size_t)n * F_NODE + 2 * lane);
  short2 hx; hx.x = f2b(xv.x); hx.y = f2b(xv.y);
  short* hrow = hin + (size_t)n * K_DIM;
  *reinterpret_cast<short2*>(hrow + 2 * lane) = hx;
  // agg part: lanes 0..31 write short4
  if (half == 0) {
    short4 hm;
    hm.x = f2b(a[0] * inv); hm.y = f2b(a[1] * inv);
    hm.z = f2b(a[2] * inv); hm.w = f2b(a[3] * inv);
    *reinterpret_cast<short4*>(hrow + F_NODE + 4 * l32) = hm;
  }
}

// ------------- Phase 3: fused MLP  out = relu(Hin@W1^T+b1)@W2^T + b2 -------
// Block: 64 rows, 256 threads (4 waves), 32 KB LDS -> short serial path,
// more blocks in flight. H1 overwrites the A-tile in the SAME LDS buffer.
// LDS byte-swizzle kb' = kb ^ ((row&15)<<5): ds_read_b128 fragments <=2-way.

__global__ __launch_bounds__(256) void k_mlp(const short* __restrict__ A,
                                             const short* __restrict__ W1b,
                                             const float* __restrict__ b1,
                                             const short* __restrict__ W2b,
                                             const float* __restrict__ b2,
                                             float* __restrict__ out, int M) {
  __shared__ short lds[64 * 256];  // 32 KB
  const int t = threadIdx.x;
  const int lane = t & 63, wid = t >> 6;
  const int mrow0 = blockIdx.x * 64;
  const int lr = lane & 15;
  const int lkb = (lane >> 4) << 4;
  char* ldsb = (char*)lds;

  // stage 64 rows x 512B; pre-swizzled global source, linear LDS dest
#pragma unroll
  for (int j = 0; j < 8; ++j) {
    int chunk = j * 256 + t;               // 16B chunk index, 32 chunks/row
    int row = chunk >> 5;
    int kb = (chunk & 31) << 4;
    int src_kb = kb ^ ((row & 15) << 5);
    int grow = mrow0 + row; grow = grow < M ? grow : M - 1;
    const char* gsrc = (const char*)A + (size_t)grow * 512 + src_kb;
    char* ldst = ldsb + (size_t)(j * 256 + wid * 64) * 16;
    gld_lds16(gsrc, ldst);
  }
  __syncthreads();

  // ---- GEMM1: H1[64x256] = relu(A @ W1^T + b1); wave = 64 rows x 64 cols ----
  const int wc = wid;  // 0..3 col quarter
  f32x4 acc1[4][4] = {};
  for (int ksb = 0; ksb < 512; ksb += 64) {
    s16x8 af[4], bf[4];
#pragma unroll
    for (int m = 0; m < 4; ++m) {
      int row = m * 16 + lr;
      int kb = (ksb + lkb) ^ ((row & 15) << 5);
      af[m] = *reinterpret_cast<const s16x8*>(ldsb + row * 512 + kb);
    }
#pragma unroll
    for (int nn = 0; nn < 4; ++nn) {
      int c = wc * 64 + nn * 16 + lr;
      bf[nn] = *reinterpret_cast<const s16x8*>(W1b + (size_t)c * 256 + ((ksb + lkb) >> 1));
    }
#pragma unroll
    for (int m = 0; m < 4; ++m)
#pragma unroll
      for (int nn = 0; nn < 4; ++nn)
        acc1[m][nn] = __builtin_amdgcn_mfma_f32_16x16x32_bf16(af[m], bf[nn], acc1[m][nn], 0, 0, 0);
  }
  __syncthreads();  // all waves done reading A before overwriting with H1

  // epilogue 1: bias+relu -> bf16 into LDS (same swizzle)
#pragma unroll
  for (int nn = 0; nn < 4; ++nn) {
    int c = wc * 64 + nn * 16 + lr;
    float bv = b1[c];
#pragma unroll
    for (int m = 0; m < 4; ++m) {
#pragma unroll
      for (int j = 0; j < 4; ++j) {
        int r = m * 16 + (lane >> 4) * 4 + j;
        float v = acc1[m][nn][j] + bv;
        v = v > 0.f ? v : 0.f;
        *reinterpret_cast<short*>(ldsb + r * 512 + ((c * 2) ^ ((r & 15) << 5))) = f2b(v);
      }
    }
  }
  __syncthreads();

  // ---- GEMM2: out[64x128] = H1 @ W2^T + b2; wave = 32 rows x 64 cols ----
  const int wr2 = wid >> 1;  // 0..1: 32-row strip
  const int wc2 = wid & 1;   // 0..1: 64-col half
  f32x4 acc2[2][4] = {};
  for (int ksb = 0; ksb < 512; ksb += 64) {
    s16x8 af[2], bf[4];
#pragma unroll
    for (int m = 0; m < 2; ++m) {
      int row = wr2 * 32 + m * 16 + lr;
      int kb = (ksb + lkb) ^ ((row & 15) << 5);
      af[m] = *reinterpret_cast<const s16x8*>(ldsb + row * 512 + kb);
    }
#pragma unroll
    for (int nn = 0; nn < 4; ++nn) {
      int c = wc2 * 64 + nn * 16 + lr;
      bf[nn] = *reinterpret_cast<const s16x8*>(W2b + (size_t)c * 256 + ((ksb + lkb) >> 1));
    }
#pragma unroll
    for (int m = 0; m < 2; ++m)
#pragma unroll
      for (int nn = 0; nn < 4; ++nn)
        acc2[m][nn] = __builtin_amdgcn_mfma_f32_16x16x32_bf16(af[m], bf[nn], acc2[m][nn], 0, 0, 0);
  }
#pragma unroll
  for (int nn = 0; nn < 4; ++nn) {
    int c = wc2 * 64 + nn * 16 + lr;
    float bv = b2[c];
#pragma unroll
    for (int m = 0; m < 2; ++m) {
#pragma unroll
      for (int j = 0; j < 4; ++j) {
        int r = mrow0 + wr2 * 32 + m * 16 + (lane >> 4) * 4 + j;
        if (r < M) out[(size_t)r * OUT_F + c] = acc2[m][nn][j] + bv;
      }
    }
  }
}

// ---------------- launch ----------------

extern "C" void kernel_launch(void* const* d_in, const int* in_sizes, int n_in,
                              void* d_out, int out_size, void* d_ws, size_t ws_size,
                              hipStream_t stream) {
  const float* x         = (const float*)d_in[0];
  const int*   edge_idx  = (const int*)d_in[1];      // [2 x N_EDGES], int32
  const int*   col       = edge_idx + N_EDGES;       // row 1 = destinations
  const float* edge_attr = (const float*)d_in[2];
  const float* W1        = (const float*)d_in[3];
  const float* b1        = (const float*)d_in[4];
  const float* W2        = (const float*)d_in[5];
  const float* b2        = (const float*)d_in[6];
  float* out = (float*)d_out;

  // workspace layout (bytes), 16B-aligned
  char* ws = (char*)d_ws;
  unsigned* cursor = (unsigned*)(ws + 0);          // 400,000
  unsigned* ids    = (unsigned*)(ws + 400000);     // 100000*64*4 = 25,600,000
  short*    hin    = (short*)   (ws + 26000000);   // 51,200,000
  short*    w1b    = (short*)   (ws + 77200000);   // 131,072
  short*    w2b    = (short*)   (ws + 77331072);   // 65,536
  // total ~77.4 MB

  hipMemsetAsync(cursor, 0, 400000, stream);

  k_fill_cvt<<<FILL_BLOCKS + CVT_BLOCKS, 256, 0, stream>>>(col, cursor, ids,
                                                           W1, W2, w1b, w2b);
  k_agg<<<(N_NODES * 64 + 255) / 256, 256, 0, stream>>>(x, edge_attr, cursor, ids, hin);
  k_mlp<<<(N_NODES + 63) / 64, 256, 0, stream>>>(hin, w1b, b1, w2b, b2, out, N_NODES);
}